// Round 12
// baseline (138.901 us; speedup 1.0000x reference)
//
#include <hip/hip_runtime.h>
#include <hip/hip_bf16.h>

#define NROWS 10000
#define KPAD  10240

typedef __attribute__((ext_vector_type(8))) short bf16x8;
typedef __attribute__((ext_vector_type(4))) float f32x4;

__device__ __forceinline__ float leaky_f(float x) { return x >= 0.f ? x : 0.01f * x; }

__device__ __forceinline__ unsigned short f2bf(float f) {
    union { float f; unsigned int u; } v; v.f = f;
    unsigned int r = v.u + 0x7fffu + ((v.u >> 16) & 1u);
    return (unsigned short)(r >> 16);
}
__device__ __forceinline__ float bf2f(unsigned short h) {
    union { unsigned int u; float f; } v; v.u = ((unsigned int)h) << 16;
    return v.f;
}

// ---------------- merged conversions + zero-init ----------------
__global__ void conv_all(const float* __restrict__ x, const float* __restrict__ W1,
                         const float* __restrict__ Wc1a, const float* __restrict__ Wc1b,
                         const float* __restrict__ Wc2a, const float* __restrict__ Wc2b,
                         const float* __restrict__ W6,
                         unsigned short* __restrict__ XHI,
                         unsigned short* __restrict__ o1, unsigned short* __restrict__ o2,
                         unsigned short* __restrict__ o3, unsigned short* __restrict__ o4,
                         unsigned short* __restrict__ o5, unsigned short* __restrict__ o6,
                         int* __restrict__ counts, unsigned short* __restrict__ Zt,
                         unsigned short* __restrict__ H2t) {
    int gid = blockIdx.x * 256 + threadIdx.x;
    if (gid < 1280000) {
        float4 v = ((const float4*)x)[gid];
        ushort4 h;
        h.x = f2bf(v.x); h.y = f2bf(v.y); h.z = f2bf(v.z); h.w = f2bf(v.w);
        ((ushort4*)XHI)[gid] = h;
    } else if (gid < 1411072) {           // W1 512x256
        int i = gid - 1280000, k = i >> 8, n = i & 255;
        o1[n * 512 + k] = f2bf(W1[i]);
    } else if (gid < 1443840) {           // Wc1a 256x128
        int i = gid - 1411072, k = i >> 7, n = i & 127;
        o2[n * 256 + k] = f2bf(Wc1a[i]);
    } else if (gid < 1452032) {           // Wc1b 128x64
        int i = gid - 1443840, k = i >> 6, n = i & 63;
        o3[n * 128 + k] = f2bf(Wc1b[i]);
    } else if (gid < 1460224) {           // Wc2a 64x128
        int i = gid - 1452032, k = i >> 7, n = i & 127;
        o4[n * 64 + k] = f2bf(Wc2a[i]);
    } else if (gid < 1492992) {           // Wc2b 128x256
        int i = gid - 1460224, k = i >> 8, n = i & 255;
        o5[n * 128 + k] = f2bf(Wc2b[i]);
    } else if (gid < 1624064) {           // W6 256x512
        int i = gid - 1492992, k = i >> 9, n = i & 511;
        o6[n * 256 + k] = f2bf(W6[i]);
    } else if (gid < 1634064) {
        counts[gid - 1624064] = 0;
    } else if (gid < 1649424) {           // ZT pad tail [64][10000..10240)
        int i = gid - 1634064;
        Zt[(size_t)(i / 240) * KPAD + 10000 + (i % 240)] = 0;
    } else if (gid < 1710864) {           // H2T pad tail [256][10000..10240)
        int i = gid - 1649424;
        H2t[(size_t)(i / 240) * KPAD + 10000 + (i % 240)] = 0;
    }
}

// ---------------- CSR build ----------------
__global__ void hist_kernel(const int* __restrict__ rows, int* __restrict__ counts, int E) {
    int i = blockIdx.x * blockDim.x + threadIdx.x;
    if (i < E) atomicAdd(&counts[rows[i]], 1);
}

__global__ __launch_bounds__(1024)
void scan_kernel(const int* __restrict__ counts, int* __restrict__ starts,
                 int* __restrict__ cursor, int n) {
    __shared__ int buf[1024];
    int tid = threadIdx.x;
    int base = tid * 10;
    int v[10];
    int local = 0;
#pragma unroll
    for (int j = 0; j < 10; ++j) {
        int i = base + j;
        v[j] = (i < n) ? counts[i] : 0;
        local += v[j];
    }
    buf[tid] = local;
    __syncthreads();
    for (int off = 1; off < 1024; off <<= 1) {
        int t = (tid >= off) ? buf[tid - off] : 0;
        __syncthreads();
        buf[tid] += t;
        __syncthreads();
    }
    int run = buf[tid] - local;
#pragma unroll
    for (int j = 0; j < 10; ++j) {
        int i = base + j;
        if (i < n) { starts[i] = run; cursor[i] = run; run += v[j]; }
    }
    if (tid == 1023) starts[n] = buf[1023];
}

// scatter edges into row-sorted packed (col, val) records
__global__ void scatter_kernel(const int* __restrict__ rows, const int* __restrict__ cols,
                               const float* __restrict__ vals, int* __restrict__ cursor,
                               int2* __restrict__ edge_s, int E) {
    int i = blockIdx.x * blockDim.x + threadIdx.x;
    if (i < E) {
        int pos = atomicAdd(&cursor[rows[i]], 1);
        edge_s[pos] = make_int2(cols[i], __float_as_int(vals[i]));
    }
}

// ---------------- SpMM: 2 edges/wave (half-wave each), 16B gathers ----------------
// lanes 0-31: edges s, s+2, ...; lanes 32-63: edges s+1, s+3, ...; 8 cols/lane.
__global__ __launch_bounds__(64)
void spmm_leaky_w2(const int* __restrict__ starts, const int2* __restrict__ edge_s,
                   const unsigned short* __restrict__ C1b, const float* __restrict__ b1,
                   unsigned short* __restrict__ Hb) {
    int r = blockIdx.x;
    int half = threadIdx.x >> 5;
    int l32 = threadIdx.x & 31;
    int cbase = l32 * 8;
    float a0[8], a1[8];
#pragma unroll
    for (int j = 0; j < 8; ++j) { a0[j] = 0.f; a1[j] = 0.f; }
    int s = starts[r], e = starts[r + 1];
    int p = s + half;
    for (; p + 2 < e; p += 4) {       // two stride-2 edges: p, p+2
        int2 e0 = edge_s[p];
        int2 e1 = edge_s[p + 2];
        float v0 = __int_as_float(e0.y);
        float v1 = __int_as_float(e1.y);
        uint4 q0 = *(const uint4*)(C1b + (size_t)e0.x * 256 + cbase);
        uint4 q1 = *(const uint4*)(C1b + (size_t)e1.x * 256 + cbase);
        a0[0] += v0 * bf2f((unsigned short)(q0.x & 0xffff));
        a0[1] += v0 * bf2f((unsigned short)(q0.x >> 16));
        a0[2] += v0 * bf2f((unsigned short)(q0.y & 0xffff));
        a0[3] += v0 * bf2f((unsigned short)(q0.y >> 16));
        a0[4] += v0 * bf2f((unsigned short)(q0.z & 0xffff));
        a0[5] += v0 * bf2f((unsigned short)(q0.z >> 16));
        a0[6] += v0 * bf2f((unsigned short)(q0.w & 0xffff));
        a0[7] += v0 * bf2f((unsigned short)(q0.w >> 16));
        a1[0] += v1 * bf2f((unsigned short)(q1.x & 0xffff));
        a1[1] += v1 * bf2f((unsigned short)(q1.x >> 16));
        a1[2] += v1 * bf2f((unsigned short)(q1.y & 0xffff));
        a1[3] += v1 * bf2f((unsigned short)(q1.y >> 16));
        a1[4] += v1 * bf2f((unsigned short)(q1.z & 0xffff));
        a1[5] += v1 * bf2f((unsigned short)(q1.z >> 16));
        a1[6] += v1 * bf2f((unsigned short)(q1.w & 0xffff));
        a1[7] += v1 * bf2f((unsigned short)(q1.w >> 16));
    }
    if (p < e) {                      // last stride-2 edge for this half
        int2 e0 = edge_s[p];
        float v0 = __int_as_float(e0.y);
        uint4 q0 = *(const uint4*)(C1b + (size_t)e0.x * 256 + cbase);
        a0[0] += v0 * bf2f((unsigned short)(q0.x & 0xffff));
        a0[1] += v0 * bf2f((unsigned short)(q0.x >> 16));
        a0[2] += v0 * bf2f((unsigned short)(q0.y & 0xffff));
        a0[3] += v0 * bf2f((unsigned short)(q0.y >> 16));
        a0[4] += v0 * bf2f((unsigned short)(q0.z & 0xffff));
        a0[5] += v0 * bf2f((unsigned short)(q0.z >> 16));
        a0[6] += v0 * bf2f((unsigned short)(q0.w & 0xffff));
        a0[7] += v0 * bf2f((unsigned short)(q0.w >> 16));
    }
    // combine halves (lane i + lane i+32), bias, leaky, write from half 0
    float f[8];
#pragma unroll
    for (int j = 0; j < 8; ++j) {
        float v = a0[j] + a1[j];
        v += __shfl_xor(v, 32);
        f[j] = v;
    }
    if (half == 0) {
        uint4 h;
        unsigned int w0 = (unsigned int)f2bf(leaky_f(f[0] + b1[cbase + 0]))
                        | ((unsigned int)f2bf(leaky_f(f[1] + b1[cbase + 1])) << 16);
        unsigned int w1 = (unsigned int)f2bf(leaky_f(f[2] + b1[cbase + 2]))
                        | ((unsigned int)f2bf(leaky_f(f[3] + b1[cbase + 3])) << 16);
        unsigned int w2 = (unsigned int)f2bf(leaky_f(f[4] + b1[cbase + 4]))
                        | ((unsigned int)f2bf(leaky_f(f[5] + b1[cbase + 5])) << 16);
        unsigned int w3 = (unsigned int)f2bf(leaky_f(f[6] + b1[cbase + 6]))
                        | ((unsigned int)f2bf(leaky_f(f[7] + b1[cbase + 7])) << 16);
        h.x = w0; h.y = w1; h.z = w2; h.w = w3;
        *(uint4*)(Hb + (size_t)r * 256 + cbase) = h;
    }
}

// ---------------- generic 64-tile MFMA GEMM ----------------
template<int ACT, int WF32, int WBF, int WTB>
__global__ __launch_bounds__(256)
void gemm_mfma(const unsigned short* __restrict__ A, const unsigned short* __restrict__ Bt,
               const float* __restrict__ bias, float* __restrict__ Cf,
               unsigned short* __restrict__ Cb, unsigned short* __restrict__ Ct,
               int ldt, int M, int N, int K) {
    __shared__ short sA[64][72];
    __shared__ short sB[64][72];
    const int bm = blockIdx.x * 64;
    const int bn = blockIdx.y * 64;
    const int tid = threadIdx.x;
    const int lane = tid & 63, wid = tid >> 6;
    const int wm = wid & 1, wn = wid >> 1;
    const int l15 = lane & 15, kg = lane >> 4;

    f32x4 acc[2][2];
#pragma unroll
    for (int i = 0; i < 2; i++)
#pragma unroll
        for (int j = 0; j < 2; j++) acc[i][j] = (f32x4){0.f, 0.f, 0.f, 0.f};

    for (int k0 = 0; k0 < K; k0 += 64) {
#pragma unroll
        for (int it = 0; it < 2; ++it) {
            int idx = tid + it * 256;
            int r = idx >> 3, s = idx & 7;
            int gm = bm + r;
            uint4 va = {0u, 0u, 0u, 0u};
            if (gm < M) va = *(const uint4*)(A + (size_t)gm * K + k0 + s * 8);
            *(uint4*)(&sA[r][s * 8]) = va;
            uint4 vb = *(const uint4*)(Bt + (size_t)(bn + r) * K + k0 + s * 8);
            *(uint4*)(&sB[r][s * 8]) = vb;
        }
        __syncthreads();
        bf16x8 a[2][2], b[2][2];
#pragma unroll
        for (int i = 0; i < 2; i++)
#pragma unroll
            for (int ks = 0; ks < 2; ++ks) {
                a[i][ks] = *(const bf16x8*)(&sA[wm * 32 + i * 16 + l15][kg * 8 + ks * 32]);
                b[i][ks] = *(const bf16x8*)(&sB[wn * 32 + i * 16 + l15][kg * 8 + ks * 32]);
            }
#pragma unroll
        for (int ks = 0; ks < 2; ++ks)
#pragma unroll
            for (int i = 0; i < 2; i++)
#pragma unroll
                for (int j = 0; j < 2; j++)
                    acc[i][j] = __builtin_amdgcn_mfma_f32_16x16x32_bf16(a[i][ks], b[j][ks], acc[i][j], 0, 0, 0);
        __syncthreads();
    }

#pragma unroll
    for (int i = 0; i < 2; i++) {
        int row0 = wm * 32 + i * 16 + kg * 4;
#pragma unroll
        for (int j = 0; j < 2; j++) {
            int col = bn + wn * 32 + j * 16 + l15;
            float bv = bias ? bias[col] : 0.f;
            ushort4 tw;
#pragma unroll
            for (int r = 0; r < 4; r++) {
                int grow = bm + row0 + r;
                float v = acc[i][j][r] + bv;
                if (ACT) v = leaky_f(v);
                if (WF32) { if (grow < M) Cf[(size_t)grow * N + col] = v; }
                if (WBF)  { if (grow < M) Cb[(size_t)grow * N + col] = f2bf(v); }
                if (WTB)  ((unsigned short*)&tw)[r] = f2bf(v);
            }
            if (WTB && (bm + row0) < M)
                *(ushort4*)(&Ct[(size_t)col * ldt + bm + row0]) = tw;
        }
    }
}

// ---------------- fused encoder tail: H -> T1 (LDS) -> z ----------------
__global__ __launch_bounds__(256)
void fused_enc(const unsigned short* __restrict__ H,   // [M][256]
               const unsigned short* __restrict__ Wa,  // [128][256]
               const unsigned short* __restrict__ Wb,  // [64][128]
               const float* __restrict__ ba, const float* __restrict__ bb,
               float* __restrict__ Zf, unsigned short* __restrict__ Zb,
               unsigned short* __restrict__ Zt, int M) {
    __shared__ short sA[64][72];
    __shared__ short sB[128][72];
    __shared__ short sT1[64][136];
    __shared__ short sWb[64][136];
    const int bm = blockIdx.x * 64;
    const int tid = threadIdx.x;
    const int lane = tid & 63, wid = tid >> 6;
    const int wm = wid & 1, wn = wid >> 1;
    const int l15 = lane & 15, kg = lane >> 4;

#pragma unroll
    for (int it = 0; it < 4; ++it) {
        int idx = tid + it * 256;
        int r = idx >> 4, s = idx & 15;
        *(uint4*)(&sWb[r][s * 8]) = *(const uint4*)(Wb + r * 128 + s * 8);
    }

    f32x4 accA[2][4];
#pragma unroll
    for (int i = 0; i < 2; i++)
#pragma unroll
        for (int j = 0; j < 4; j++) accA[i][j] = (f32x4){0.f, 0.f, 0.f, 0.f};

    for (int k0 = 0; k0 < 256; k0 += 64) {
#pragma unroll
        for (int it = 0; it < 2; ++it) {
            int idx = tid + it * 256;
            int r = idx >> 3, s = idx & 7;
            int gm = bm + r;
            uint4 va = {0u, 0u, 0u, 0u};
            if (gm < M) va = *(const uint4*)(H + (size_t)gm * 256 + k0 + s * 8);
            *(uint4*)(&sA[r][s * 8]) = va;
        }
#pragma unroll
        for (int it = 0; it < 4; ++it) {
            int idx = tid + it * 256;
            int r = idx >> 3, s = idx & 7;
            *(uint4*)(&sB[r][s * 8]) = *(const uint4*)(Wa + r * 256 + k0 + s * 8);
        }
        __syncthreads();
#pragma unroll
        for (int ks = 0; ks < 2; ++ks) {
            bf16x8 a[2], b[4];
#pragma unroll
            for (int i = 0; i < 2; i++)
                a[i] = *(const bf16x8*)(&sA[wm * 32 + i * 16 + l15][kg * 8 + ks * 32]);
#pragma unroll
            for (int j = 0; j < 4; j++)
                b[j] = *(const bf16x8*)(&sB[wn * 64 + j * 16 + l15][kg * 8 + ks * 32]);
#pragma unroll
            for (int i = 0; i < 2; i++)
#pragma unroll
                for (int j = 0; j < 4; j++)
                    accA[i][j] = __builtin_amdgcn_mfma_f32_16x16x32_bf16(a[i], b[j], accA[i][j], 0, 0, 0);
        }
        __syncthreads();
    }
#pragma unroll
    for (int i = 0; i < 2; i++) {
        int row0 = wm * 32 + i * 16 + kg * 4;
#pragma unroll
        for (int j = 0; j < 4; j++) {
            int col = wn * 64 + j * 16 + l15;
            float bv = ba[col];
#pragma unroll
            for (int r = 0; r < 4; r++)
                sT1[row0 + r][col] = f2bf(leaky_f(accA[i][j][r] + bv));
        }
    }
    __syncthreads();

    f32x4 accB[2][2];
#pragma unroll
    for (int i = 0; i < 2; i++)
#pragma unroll
        for (int j = 0; j < 2; j++) accB[i][j] = (f32x4){0.f, 0.f, 0.f, 0.f};
#pragma unroll
    for (int kc = 0; kc < 4; ++kc) {
        bf16x8 a[2], b[2];
#pragma unroll
        for (int i = 0; i < 2; i++)
            a[i] = *(const bf16x8*)(&sT1[wm * 32 + i * 16 + l15][kc * 32 + kg * 8]);
#pragma unroll
        for (int j = 0; j < 2; j++)
            b[j] = *(const bf16x8*)(&sWb[wn * 32 + j * 16 + l15][kc * 32 + kg * 8]);
#pragma unroll
        for (int i = 0; i < 2; i++)
#pragma unroll
            for (int j = 0; j < 2; j++)
                accB[i][j] = __builtin_amdgcn_mfma_f32_16x16x32_bf16(a[i], b[j], accB[i][j], 0, 0, 0);
    }
#pragma unroll
    for (int i = 0; i < 2; i++) {
        int row0 = wm * 32 + i * 16 + kg * 4;
#pragma unroll
        for (int j = 0; j < 2; j++) {
            int col = wn * 32 + j * 16 + l15;
            float bv = bb[col];
            ushort4 tw;
#pragma unroll
            for (int r = 0; r < 4; r++) {
                int grow = bm + row0 + r;
                float v = accB[i][j][r] + bv;
                if (grow < M) {
                    Zf[(size_t)grow * 64 + col] = v;
                    Zb[(size_t)grow * 64 + col] = f2bf(v);
                }
                ((unsigned short*)&tw)[r] = f2bf(v);
            }
            if ((bm + row0) < M)
                *(ushort4*)(&Zt[(size_t)col * KPAD + bm + row0]) = tw;
        }
    }
}

// ---------------- fused decoder head: z -> T2 (LDS) -> H2^T ----------------
__global__ __launch_bounds__(256)
void fused_dec(const unsigned short* __restrict__ Z,   // [M][64]
               const unsigned short* __restrict__ Wa,  // [128][64]
               const unsigned short* __restrict__ Wb,  // [256][128]
               const float* __restrict__ ba, const float* __restrict__ bb,
               unsigned short* __restrict__ H2t, int M) {
    __shared__ short sA[64][72];
    __shared__ short sB[128][72];
    __shared__ short sT2[64][136];
    __shared__ short sB2[256][72];
    const int bm = blockIdx.x * 64;
    const int tid = threadIdx.x;
    const int lane = tid & 63, wid = tid >> 6;
    const int wm = wid & 1, wn = wid >> 1;
    const int l15 = lane & 15, kg = lane >> 4;

#pragma unroll
    for (int it = 0; it < 2; ++it) {
        int idx = tid + it * 256;
        int r = idx >> 3, s = idx & 7;
        int gm = bm + r;
        uint4 va = {0u, 0u, 0u, 0u};
        if (gm < M) va = *(const uint4*)(Z + (size_t)gm * 64 + s * 8);
        *(uint4*)(&sA[r][s * 8]) = va;
    }
#pragma unroll
    for (int it = 0; it < 4; ++it) {
        int idx = tid + it * 256;
        int r = idx >> 3, s = idx & 7;
        *(uint4*)(&sB[r][s * 8]) = *(const uint4*)(Wa + r * 64 + s * 8);
    }
    __syncthreads();
    f32x4 accA[2][4];
#pragma unroll
    for (int i = 0; i < 2; i++)
#pragma unroll
        for (int j = 0; j < 4; j++) accA[i][j] = (f32x4){0.f, 0.f, 0.f, 0.f};
#pragma unroll
    for (int ks = 0; ks < 2; ++ks) {
        bf16x8 a[2], b[4];
#pragma unroll
        for (int i = 0; i < 2; i++)
            a[i] = *(const bf16x8*)(&sA[wm * 32 + i * 16 + l15][kg * 8 + ks * 32]);
#pragma unroll
        for (int j = 0; j < 4; j++)
            b[j] = *(const bf16x8*)(&sB[wn * 64 + j * 16 + l15][kg * 8 + ks * 32]);
#pragma unroll
        for (int i = 0; i < 2; i++)
#pragma unroll
            for (int j = 0; j < 4; j++)
                accA[i][j] = __builtin_amdgcn_mfma_f32_16x16x32_bf16(a[i], b[j], accA[i][j], 0, 0, 0);
    }
    __syncthreads();
#pragma unroll
    for (int i = 0; i < 2; i++) {
        int row0 = wm * 32 + i * 16 + kg * 4;
#pragma unroll
        for (int j = 0; j < 4; j++) {
            int col = wn * 64 + j * 16 + l15;
            float bv = ba[col];
#pragma unroll
            for (int r = 0; r < 4; r++)
                sT2[row0 + r][col] = f2bf(leaky_f(accA[i][j][r] + bv));
        }
    }
    __syncthreads();

    f32x4 accB[2][8];
#pragma unroll
    for (int i = 0; i < 2; i++)
#pragma unroll
        for (int j = 0; j < 8; j++) accB[i][j] = (f32x4){0.f, 0.f, 0.f, 0.f};
    for (int k0 = 0; k0 < 128; k0 += 64) {
#pragma unroll
        for (int it = 0; it < 8; ++it) {
            int idx = tid + it * 256;
            int r = idx >> 3, s = idx & 7;
            *(uint4*)(&sB2[r][s * 8]) = *(const uint4*)(Wb + r * 128 + k0 + s * 8);
        }
        __syncthreads();
#pragma unroll
        for (int ks = 0; ks < 2; ++ks) {
            bf16x8 a[2], b[8];
#pragma unroll
            for (int i = 0; i < 2; i++)
                a[i] = *(const bf16x8*)(&sT2[wm * 32 + i * 16 + l15][k0 + ks * 32 + kg * 8]);
#pragma unroll
            for (int j = 0; j < 8; j++)
                b[j] = *(const bf16x8*)(&sB2[wn * 128 + j * 16 + l15][kg * 8 + ks * 32]);
#pragma unroll
            for (int i = 0; i < 2; i++)
#pragma unroll
                for (int j = 0; j < 8; j++)
                    accB[i][j] = __builtin_amdgcn_mfma_f32_16x16x32_bf16(a[i], b[j], accB[i][j], 0, 0, 0);
        }
        __syncthreads();
    }
#pragma unroll
    for (int i = 0; i < 2; i++) {
        int row0 = wm * 32 + i * 16 + kg * 4;
#pragma unroll
        for (int j = 0; j < 8; j++) {
            int col = wn * 128 + j * 16 + l15;
            float bv = bb[col];
            ushort4 tw;
#pragma unroll
            for (int r = 0; r < 4; r++)
                ((unsigned short*)&tw)[r] = f2bf(leaky_f(accB[i][j][r] + bv));
            if ((bm + row0) < M)
                *(ushort4*)(&H2t[(size_t)col * KPAD + bm + row0]) = tw;
        }
    }
}

// ---------------- S2 split-K MFMA: 40 splits of 256 ----------------
__global__ __launch_bounds__(256)
void sgemm_sk(const unsigned short* __restrict__ Zt, const unsigned short* __restrict__ H2t,
              float* __restrict__ part) {
    __shared__ short sA[64][72];
    __shared__ short sB[64][72];
    const int bn = blockIdx.x * 64;
    const int kc = blockIdx.y;
    const int tid = threadIdx.x;
    const int lane = tid & 63, wid = tid >> 6;
    const int wm = wid & 1, wn = wid >> 1;
    const int l15 = lane & 15, kg = lane >> 4;

    f32x4 acc[2][2];
#pragma unroll
    for (int i = 0; i < 2; i++)
#pragma unroll
        for (int j = 0; j < 2; j++) acc[i][j] = (f32x4){0.f, 0.f, 0.f, 0.f};

    for (int kk = 0; kk < 4; ++kk) {
        int k0 = kc * 256 + kk * 64;
#pragma unroll
        for (int it = 0; it < 2; ++it) {
            int idx = tid + it * 256;
            int r = idx >> 3, s = idx & 7;
            *(uint4*)(&sA[r][s * 8]) = *(const uint4*)(Zt + (size_t)r * KPAD + k0 + s * 8);
            *(uint4*)(&sB[r][s * 8]) = *(const uint4*)(H2t + (size_t)(bn + r) * KPAD + k0 + s * 8);
        }
        __syncthreads();
        bf16x8 a[2][2], b[2][2];
#pragma unroll
        for (int i = 0; i < 2; i++)
#pragma unroll
            for (int ks = 0; ks < 2; ++ks) {
                a[i][ks] = *(const bf16x8*)(&sA[wm * 32 + i * 16 + l15][kg * 8 + ks * 32]);
                b[i][ks] = *(const bf16x8*)(&sB[wn * 32 + i * 16 + l15][kg * 8 + ks * 32]);
            }
#pragma unroll
        for (int ks = 0; ks < 2; ++ks)
#pragma unroll
            for (int i = 0; i < 2; i++)
#pragma unroll
                for (int j = 0; j < 2; j++)
                    acc[i][j] = __builtin_amdgcn_mfma_f32_16x16x32_bf16(a[i][ks], b[j][ks], acc[i][j], 0, 0, 0);
        __syncthreads();
    }
#pragma unroll
    for (int i = 0; i < 2; i++) {
        int row0 = wm * 32 + i * 16 + kg * 4;
#pragma unroll
        for (int j = 0; j < 2; j++) {
            int col = bn + wn * 32 + j * 16 + l15;
#pragma unroll
            for (int r = 0; r < 4; r++)
                part[((size_t)kc * 64 + row0 + r) * 256 + col] = acc[i][j][r];
        }
    }
}

// reduce 40 partials -> S2 bf16 [64][256]
__global__ void reduce_S2(const float* __restrict__ part, unsigned short* __restrict__ S2b) {
    int i = blockIdx.x * blockDim.x + threadIdx.x;
    if (i < 64 * 256) {
        float s = 0.f;
#pragma unroll
        for (int c = 0; c < 40; ++c) s += part[(size_t)c * (64 * 256) + i];
        S2b[i] = f2bf(s);
    }
}

// ---------------- launch ----------------
extern "C" void kernel_launch(void* const* d_in, const int* in_sizes, int n_in,
                              void* d_out, int out_size, void* d_ws, size_t ws_size,
                              hipStream_t stream) {
    const float* x    = (const float*)d_in[0];
    const int*   rows = (const int*)d_in[1];
    const int*   cols = (const int*)d_in[2];
    const float* vals = (const float*)d_in[3];
    const float* W1   = (const float*)d_in[4];
    const float* b1   = (const float*)d_in[5];
    const float* Wc1a = (const float*)d_in[6];
    const float* bc1a = (const float*)d_in[7];
    const float* Wc1b = (const float*)d_in[8];
    const float* bc1b = (const float*)d_in[9];
    const float* Wc2a = (const float*)d_in[10];
    const float* bc2a = (const float*)d_in[11];
    const float* Wc2b = (const float*)d_in[12];
    const float* bc2b = (const float*)d_in[13];
    const float* W6   = (const float*)d_in[14];
    const float* b6   = (const float*)d_in[15];

    const int N = NROWS;
    const int E = in_sizes[1];

    float* ws = (float*)d_ws;
    unsigned short* XHI  = (unsigned short*)(ws + 0);         // [10000][512]
    unsigned short* C1b  = (unsigned short*)(ws + 2560000);   // [10000][256]
    unsigned short* HHI  = (unsigned short*)(ws + 3840000);   // [10000][256]
    unsigned short* ZHI  = (unsigned short*)(ws + 5120000);   // [10000][64]
    unsigned short* ZT   = (unsigned short*)(ws + 5440000);   // [64][10240]
    unsigned short* H2T  = (unsigned short*)(ws + 5767680);   // [256][10240]
    float*          PART = ws + 7078400;                      // [40][64][256]
    unsigned short* S2B  = (unsigned short*)(ws + 7733760);   // [64][256]
    unsigned short* W6ST = (unsigned short*)(ws + 7741952);   // [512][64]
    unsigned short* W1T   = (unsigned short*)(ws + 7758336);  // [256][512]
    unsigned short* WC1AT = (unsigned short*)(ws + 7823872);  // [128][256]
    unsigned short* WC1BT = (unsigned short*)(ws + 7840256);  // [64][128]
    unsigned short* WC2AT = (unsigned short*)(ws + 7844352);  // [128][64]
    unsigned short* WC2BT = (unsigned short*)(ws + 7848448);  // [256][128]
    unsigned short* W6T   = (unsigned short*)(ws + 7864832);  // [512][256]

    int*   counts = (int*)(ws + 7930368);
    int*   starts = counts + 10000;
    int*   cursor = starts + 10001;
    int2*  edge_s = (int2*)(cursor + 10000);   // [E] packed (col, val)

    float* Out = (float*)d_out;
    float* Zp  = (float*)d_out + 5120000;

    const int GX = (N + 63) / 64;  // 157

    conv_all<<<6683, 256, 0, stream>>>(x, W1, Wc1a, Wc1b, Wc2a, Wc2b, W6, XHI,
                                       W1T, WC1AT, WC1BT, WC2AT, WC2BT, W6T,
                                       counts, ZT, H2T);

    hist_kernel<<<(E + 255) / 256, 256, 0, stream>>>(rows, counts, E);
    scan_kernel<<<1, 1024, 0, stream>>>(counts, starts, cursor, N);
    scatter_kernel<<<(E + 255) / 256, 256, 0, stream>>>(rows, cols, vals, cursor, edge_s, E);

    // C1 = x @ W1 -> bf16 (64-tile)
    gemm_mfma<0,0,1,0><<<dim3(GX, 4), 256, 0, stream>>>(XHI, W1T, nullptr,
                                                        nullptr, C1b, nullptr, 0, N, 256, 512);

    // H = leaky(spmm + b1) -> bf16 (2 edges/wave, 16B gathers)
    spmm_leaky_w2<<<N, 64, 0, stream>>>(starts, edge_s, C1b, b1, HHI);

    // z = leaky(H@Wc1a+b)@Wc1b + b -> Zp f32, ZHI bf16, ZT bf16
    fused_enc<<<GX, 256, 0, stream>>>(HHI, WC1AT, WC1BT, bc1a, bc1b, Zp, ZHI, ZT, N);

    // H2^T -> bf16 [256][KPAD]
    fused_dec<<<GX, 256, 0, stream>>>(ZHI, WC2AT, WC2BT, bc2a, bc2b, H2T, N);

    // S2 = z^T @ H2 (split-K 40) -> PART -> S2B [64][256]
    sgemm_sk<<<dim3(4, 40), 256, 0, stream>>>(ZT, H2T, PART);
    reduce_S2<<<64, 256, 0, stream>>>(PART, S2B);

    // W6S = S2 @ W6 -> W6ST [512][64]
    gemm_mfma<0,0,0,1><<<dim3(1, 8), 256, 0, stream>>>(S2B, W6T, nullptr,
                                                       nullptr, nullptr, W6ST, 64, 64, 512, 256);

    // out = z @ W6S + b6 -> f32 (64-tile)
    gemm_mfma<0,1,0,0><<<dim3(GX, 8), 256, 0, stream>>>(ZHI, W6ST, b6,
                                                        Out, nullptr, nullptr, 0, N, 512, 64);
}

// Round 13
// 133.625 us; speedup vs baseline: 1.0395x; 1.0395x over previous
//
#include <hip/hip_runtime.h>
#include <hip/hip_bf16.h>

#define NROWS 10000
#define KPAD  10240

typedef __attribute__((ext_vector_type(8))) short bf16x8;
typedef __attribute__((ext_vector_type(4))) float f32x4;

__device__ __forceinline__ float leaky_f(float x) { return x >= 0.f ? x : 0.01f * x; }

__device__ __forceinline__ unsigned short f2bf(float f) {
    union { float f; unsigned int u; } v; v.f = f;
    unsigned int r = v.u + 0x7fffu + ((v.u >> 16) & 1u);
    return (unsigned short)(r >> 16);
}
__device__ __forceinline__ float bf2f(unsigned short h) {
    union { unsigned int u; float f; } v; v.u = ((unsigned int)h) << 16;
    return v.f;
}

// ---------------- merged conversions + zero-init ----------------
__global__ void conv_all(const float* __restrict__ x, const float* __restrict__ W1,
                         const float* __restrict__ Wc1a, const float* __restrict__ Wc1b,
                         const float* __restrict__ Wc2a, const float* __restrict__ Wc2b,
                         const float* __restrict__ W6,
                         unsigned short* __restrict__ XHI,
                         unsigned short* __restrict__ o1, unsigned short* __restrict__ o2,
                         unsigned short* __restrict__ o3, unsigned short* __restrict__ o4,
                         unsigned short* __restrict__ o5, unsigned short* __restrict__ o6,
                         int* __restrict__ counts, unsigned short* __restrict__ Zt,
                         unsigned short* __restrict__ H2t) {
    int gid = blockIdx.x * 256 + threadIdx.x;
    if (gid < 1280000) {
        float4 v = ((const float4*)x)[gid];
        ushort4 h;
        h.x = f2bf(v.x); h.y = f2bf(v.y); h.z = f2bf(v.z); h.w = f2bf(v.w);
        ((ushort4*)XHI)[gid] = h;
    } else if (gid < 1411072) {           // W1 512x256
        int i = gid - 1280000, k = i >> 8, n = i & 255;
        o1[n * 512 + k] = f2bf(W1[i]);
    } else if (gid < 1443840) {           // Wc1a 256x128
        int i = gid - 1411072, k = i >> 7, n = i & 127;
        o2[n * 256 + k] = f2bf(Wc1a[i]);
    } else if (gid < 1452032) {           // Wc1b 128x64
        int i = gid - 1443840, k = i >> 6, n = i & 63;
        o3[n * 128 + k] = f2bf(Wc1b[i]);
    } else if (gid < 1460224) {           // Wc2a 64x128
        int i = gid - 1452032, k = i >> 7, n = i & 127;
        o4[n * 64 + k] = f2bf(Wc2a[i]);
    } else if (gid < 1492992) {           // Wc2b 128x256
        int i = gid - 1460224, k = i >> 8, n = i & 255;
        o5[n * 128 + k] = f2bf(Wc2b[i]);
    } else if (gid < 1624064) {           // W6 256x512
        int i = gid - 1492992, k = i >> 9, n = i & 511;
        o6[n * 256 + k] = f2bf(W6[i]);
    } else if (gid < 1634064) {
        counts[gid - 1624064] = 0;
    } else if (gid < 1649424) {           // ZT pad tail [64][10000..10240)
        int i = gid - 1634064;
        Zt[(size_t)(i / 240) * KPAD + 10000 + (i % 240)] = 0;
    } else if (gid < 1710864) {           // H2T pad tail [256][10000..10240)
        int i = gid - 1649424;
        H2t[(size_t)(i / 240) * KPAD + 10000 + (i % 240)] = 0;
    }
}

// ---------------- CSR build ----------------
__global__ void hist_kernel(const int* __restrict__ rows, int* __restrict__ counts, int E) {
    int i = blockIdx.x * blockDim.x + threadIdx.x;
    if (i < E) atomicAdd(&counts[rows[i]], 1);
}

__global__ __launch_bounds__(1024)
void scan_kernel(const int* __restrict__ counts, int* __restrict__ starts,
                 int* __restrict__ cursor, int n) {
    __shared__ int buf[1024];
    int tid = threadIdx.x;
    int base = tid * 10;
    int v[10];
    int local = 0;
#pragma unroll
    for (int j = 0; j < 10; ++j) {
        int i = base + j;
        v[j] = (i < n) ? counts[i] : 0;
        local += v[j];
    }
    buf[tid] = local;
    __syncthreads();
    for (int off = 1; off < 1024; off <<= 1) {
        int t = (tid >= off) ? buf[tid - off] : 0;
        __syncthreads();
        buf[tid] += t;
        __syncthreads();
    }
    int run = buf[tid] - local;
#pragma unroll
    for (int j = 0; j < 10; ++j) {
        int i = base + j;
        if (i < n) { starts[i] = run; cursor[i] = run; run += v[j]; }
    }
    if (tid == 1023) starts[n] = buf[1023];
}

__global__ void scatter_kernel(const int* __restrict__ rows, const int* __restrict__ cols,
                               const float* __restrict__ vals, int* __restrict__ cursor,
                               int* __restrict__ cols_s, float* __restrict__ vals_s, int E) {
    int i = blockIdx.x * blockDim.x + threadIdx.x;
    if (i < E) {
        int pos = atomicAdd(&cursor[rows[i]], 1);
        cols_s[pos] = cols[i];
        vals_s[pos] = vals[i];
    }
}

// ---------------- SpMM (round-7 exact: 64-thread blocks, 1 row/block, 4-way unroll) ----------------
__global__ __launch_bounds__(64)
void spmm_leaky_kernel(const int* __restrict__ starts, const int* __restrict__ cols_s,
                       const float* __restrict__ vals_s, const unsigned short* __restrict__ C1b,
                       const float* __restrict__ b1, unsigned short* __restrict__ Hb) {
    int r = blockIdx.x;
    int t = threadIdx.x;
    float4 a0 = ((const float4*)b1)[t];
    float4 a1 = {0.f, 0.f, 0.f, 0.f};
    float4 a2 = {0.f, 0.f, 0.f, 0.f};
    float4 a3 = {0.f, 0.f, 0.f, 0.f};
    int s = starts[r], e = starts[r + 1];
    int p = s;
    for (; p + 4 <= e; p += 4) {
        int c0 = cols_s[p], c1 = cols_s[p + 1], c2 = cols_s[p + 2], c3 = cols_s[p + 3];
        float v0 = vals_s[p], v1 = vals_s[p + 1], v2 = vals_s[p + 2], v3 = vals_s[p + 3];
        ushort4 s0 = ((const ushort4*)(C1b + (size_t)c0 * 256))[t];
        ushort4 s1 = ((const ushort4*)(C1b + (size_t)c1 * 256))[t];
        ushort4 s2 = ((const ushort4*)(C1b + (size_t)c2 * 256))[t];
        ushort4 s3 = ((const ushort4*)(C1b + (size_t)c3 * 256))[t];
        a0.x += v0 * bf2f(s0.x); a0.y += v0 * bf2f(s0.y);
        a0.z += v0 * bf2f(s0.z); a0.w += v0 * bf2f(s0.w);
        a1.x += v1 * bf2f(s1.x); a1.y += v1 * bf2f(s1.y);
        a1.z += v1 * bf2f(s1.z); a1.w += v1 * bf2f(s1.w);
        a2.x += v2 * bf2f(s2.x); a2.y += v2 * bf2f(s2.y);
        a2.z += v2 * bf2f(s2.z); a2.w += v2 * bf2f(s2.w);
        a3.x += v3 * bf2f(s3.x); a3.y += v3 * bf2f(s3.y);
        a3.z += v3 * bf2f(s3.z); a3.w += v3 * bf2f(s3.w);
    }
    for (; p < e; ++p) {
        int c0 = cols_s[p];
        float v0 = vals_s[p];
        ushort4 s0 = ((const ushort4*)(C1b + (size_t)c0 * 256))[t];
        a0.x += v0 * bf2f(s0.x); a0.y += v0 * bf2f(s0.y);
        a0.z += v0 * bf2f(s0.z); a0.w += v0 * bf2f(s0.w);
    }
    ushort4 h;
    h.x = f2bf(leaky_f(a0.x + a1.x + a2.x + a3.x));
    h.y = f2bf(leaky_f(a0.y + a1.y + a2.y + a3.y));
    h.z = f2bf(leaky_f(a0.z + a1.z + a2.z + a3.z));
    h.w = f2bf(leaky_f(a0.w + a1.w + a2.w + a3.w));
    ((ushort4*)Hb)[(size_t)r * 64 + t] = h;
}

// ---------------- generic 64-tile MFMA GEMM ----------------
template<int ACT, int WF32, int WBF, int WTB>
__global__ __launch_bounds__(256)
void gemm_mfma(const unsigned short* __restrict__ A, const unsigned short* __restrict__ Bt,
               const float* __restrict__ bias, float* __restrict__ Cf,
               unsigned short* __restrict__ Cb, unsigned short* __restrict__ Ct,
               int ldt, int M, int N, int K) {
    __shared__ short sA[64][72];
    __shared__ short sB[64][72];
    const int bm = blockIdx.x * 64;
    const int bn = blockIdx.y * 64;
    const int tid = threadIdx.x;
    const int lane = tid & 63, wid = tid >> 6;
    const int wm = wid & 1, wn = wid >> 1;
    const int l15 = lane & 15, kg = lane >> 4;

    f32x4 acc[2][2];
#pragma unroll
    for (int i = 0; i < 2; i++)
#pragma unroll
        for (int j = 0; j < 2; j++) acc[i][j] = (f32x4){0.f, 0.f, 0.f, 0.f};

    for (int k0 = 0; k0 < K; k0 += 64) {
#pragma unroll
        for (int it = 0; it < 2; ++it) {
            int idx = tid + it * 256;
            int r = idx >> 3, s = idx & 7;
            int gm = bm + r;
            uint4 va = {0u, 0u, 0u, 0u};
            if (gm < M) va = *(const uint4*)(A + (size_t)gm * K + k0 + s * 8);
            *(uint4*)(&sA[r][s * 8]) = va;
            uint4 vb = *(const uint4*)(Bt + (size_t)(bn + r) * K + k0 + s * 8);
            *(uint4*)(&sB[r][s * 8]) = vb;
        }
        __syncthreads();
        bf16x8 a[2][2], b[2][2];
#pragma unroll
        for (int i = 0; i < 2; i++)
#pragma unroll
            for (int ks = 0; ks < 2; ++ks) {
                a[i][ks] = *(const bf16x8*)(&sA[wm * 32 + i * 16 + l15][kg * 8 + ks * 32]);
                b[i][ks] = *(const bf16x8*)(&sB[wn * 32 + i * 16 + l15][kg * 8 + ks * 32]);
            }
#pragma unroll
        for (int ks = 0; ks < 2; ++ks)
#pragma unroll
            for (int i = 0; i < 2; i++)
#pragma unroll
                for (int j = 0; j < 2; j++)
                    acc[i][j] = __builtin_amdgcn_mfma_f32_16x16x32_bf16(a[i][ks], b[j][ks], acc[i][j], 0, 0, 0);
        __syncthreads();
    }

#pragma unroll
    for (int i = 0; i < 2; i++) {
        int row0 = wm * 32 + i * 16 + kg * 4;
#pragma unroll
        for (int j = 0; j < 2; j++) {
            int col = bn + wn * 32 + j * 16 + l15;
            float bv = bias ? bias[col] : 0.f;
            ushort4 tw;
#pragma unroll
            for (int r = 0; r < 4; r++) {
                int grow = bm + row0 + r;
                float v = acc[i][j][r] + bv;
                if (ACT) v = leaky_f(v);
                if (WF32) { if (grow < M) Cf[(size_t)grow * N + col] = v; }
                if (WBF)  { if (grow < M) Cb[(size_t)grow * N + col] = f2bf(v); }
                if (WTB)  ((unsigned short*)&tw)[r] = f2bf(v);
            }
            if (WTB && (bm + row0) < M)
                *(ushort4*)(&Ct[(size_t)col * ldt + bm + row0]) = tw;
        }
    }
}

// ---------------- fused encoder tail + decoder head ----------------
// H -> T1(LDS) -> z (write Zf/Zb/Zt, keep in LDS) -> T2(LDS) -> H2^T
__global__ __launch_bounds__(256)
void fused_encdec(const unsigned short* __restrict__ H,    // [M][256]
                  const unsigned short* __restrict__ Wa,   // Wc1a^T [128][256]
                  const unsigned short* __restrict__ Wb,   // Wc1b^T [64][128]
                  const unsigned short* __restrict__ Wc,   // Wc2a^T [128][64]
                  const unsigned short* __restrict__ Wd,   // Wc2b^T [256][128]
                  const float* __restrict__ ba, const float* __restrict__ bb,
                  const float* __restrict__ bc, const float* __restrict__ bd,
                  float* __restrict__ Zf, unsigned short* __restrict__ Zb,
                  unsigned short* __restrict__ Zt, unsigned short* __restrict__ H2t,
                  int M) {
    __shared__ short sA[64][72];     // H tile staging
    __shared__ short sB[128][72];    // Wc1a slices, then Wc2a
    __shared__ short sT[64][136];    // T1, then T2
    __shared__ short sWb[64][136];   // Wc1b (whole)
    __shared__ short sZ[64][72];     // z bf16 for decoder
    __shared__ short sB2[256][72];   // Wc2b slices
    const int bm = blockIdx.x * 64;
    const int tid = threadIdx.x;
    const int lane = tid & 63, wid = tid >> 6;
    const int wm = wid & 1, wn = wid >> 1;
    const int l15 = lane & 15, kg = lane >> 4;

    // stage Wc1b whole (64x128 = 1024 uint4)
#pragma unroll
    for (int it = 0; it < 4; ++it) {
        int idx = tid + it * 256;
        int r = idx >> 4, s = idx & 15;
        *(uint4*)(&sWb[r][s * 8]) = *(const uint4*)(Wb + r * 128 + s * 8);
    }

    // ---- enc phase A: T1[64][128] = leaky(H @ Wc1a + ba), K=256 ----
    f32x4 accA[2][4];
#pragma unroll
    for (int i = 0; i < 2; i++)
#pragma unroll
        for (int j = 0; j < 4; j++) accA[i][j] = (f32x4){0.f, 0.f, 0.f, 0.f};

    for (int k0 = 0; k0 < 256; k0 += 64) {
#pragma unroll
        for (int it = 0; it < 2; ++it) {
            int idx = tid + it * 256;
            int r = idx >> 3, s = idx & 7;
            int gm = bm + r;
            uint4 va = {0u, 0u, 0u, 0u};
            if (gm < M) va = *(const uint4*)(H + (size_t)gm * 256 + k0 + s * 8);
            *(uint4*)(&sA[r][s * 8]) = va;
        }
#pragma unroll
        for (int it = 0; it < 4; ++it) {
            int idx = tid + it * 256;
            int r = idx >> 3, s = idx & 7;
            *(uint4*)(&sB[r][s * 8]) = *(const uint4*)(Wa + r * 256 + k0 + s * 8);
        }
        __syncthreads();
#pragma unroll
        for (int ks = 0; ks < 2; ++ks) {
            bf16x8 a[2], b[4];
#pragma unroll
            for (int i = 0; i < 2; i++)
                a[i] = *(const bf16x8*)(&sA[wm * 32 + i * 16 + l15][kg * 8 + ks * 32]);
#pragma unroll
            for (int j = 0; j < 4; j++)
                b[j] = *(const bf16x8*)(&sB[wn * 64 + j * 16 + l15][kg * 8 + ks * 32]);
#pragma unroll
            for (int i = 0; i < 2; i++)
#pragma unroll
                for (int j = 0; j < 4; j++)
                    accA[i][j] = __builtin_amdgcn_mfma_f32_16x16x32_bf16(a[i], b[j], accA[i][j], 0, 0, 0);
        }
        __syncthreads();
    }
#pragma unroll
    for (int i = 0; i < 2; i++) {
        int row0 = wm * 32 + i * 16 + kg * 4;
#pragma unroll
        for (int j = 0; j < 4; j++) {
            int col = wn * 64 + j * 16 + l15;
            float bv = ba[col];
#pragma unroll
            for (int r = 0; r < 4; r++)
                sT[row0 + r][col] = f2bf(leaky_f(accA[i][j][r] + bv));
        }
    }
    // stage Wc2a into sB rows 0..127 (safe: all waves past last sB read via loop-end sync... need barrier before overwrite)
    __syncthreads();
#pragma unroll
    for (int it = 0; it < 4; ++it) {
        int idx = tid + it * 256;
        int r = idx >> 3, s = idx & 7;
        *(uint4*)(&sB[r][s * 8]) = *(const uint4*)(Wc + r * 64 + s * 8);
    }

    // ---- enc phase B: z[64][64] = T1 @ Wc1b + bb ----
    f32x4 accB[2][2];
#pragma unroll
    for (int i = 0; i < 2; i++)
#pragma unroll
        for (int j = 0; j < 2; j++) accB[i][j] = (f32x4){0.f, 0.f, 0.f, 0.f};
#pragma unroll
    for (int kc = 0; kc < 4; ++kc) {
        bf16x8 a[2], b[2];
#pragma unroll
        for (int i = 0; i < 2; i++)
            a[i] = *(const bf16x8*)(&sT[wm * 32 + i * 16 + l15][kc * 32 + kg * 8]);
#pragma unroll
        for (int j = 0; j < 2; j++)
            b[j] = *(const bf16x8*)(&sWb[wn * 32 + j * 16 + l15][kc * 32 + kg * 8]);
#pragma unroll
        for (int i = 0; i < 2; i++)
#pragma unroll
            for (int j = 0; j < 2; j++)
                accB[i][j] = __builtin_amdgcn_mfma_f32_16x16x32_bf16(a[i], b[j], accB[i][j], 0, 0, 0);
    }
#pragma unroll
    for (int i = 0; i < 2; i++) {
        int row0 = wm * 32 + i * 16 + kg * 4;
#pragma unroll
        for (int j = 0; j < 2; j++) {
            int col = wn * 32 + j * 16 + l15;
            float bv = bb[col];
            ushort4 tw;
#pragma unroll
            for (int r = 0; r < 4; r++) {
                int grow = bm + row0 + r;
                float v = accB[i][j][r] + bv;
                unsigned short zb = f2bf(v);
                if (grow < M) {
                    Zf[(size_t)grow * 64 + col] = v;
                    Zb[(size_t)grow * 64 + col] = zb;
                }
                sZ[row0 + r][col] = (short)zb;
                ((unsigned short*)&tw)[r] = zb;
            }
            if ((bm + row0) < M)
                *(ushort4*)(&Zt[(size_t)col * KPAD + bm + row0]) = tw;
        }
    }
    __syncthreads();   // sZ + sB(Wc2a) ready for decoder

    // ---- dec phase A: T2[64][128] = leaky(z @ Wc2a + bc), K=64 ----
    f32x4 accC[2][4];
#pragma unroll
    for (int i = 0; i < 2; i++)
#pragma unroll
        for (int j = 0; j < 4; j++) accC[i][j] = (f32x4){0.f, 0.f, 0.f, 0.f};
#pragma unroll
    for (int ks = 0; ks < 2; ++ks) {
        bf16x8 a[2], b[4];
#pragma unroll
        for (int i = 0; i < 2; i++)
            a[i] = *(const bf16x8*)(&sZ[wm * 32 + i * 16 + l15][kg * 8 + ks * 32]);
#pragma unroll
        for (int j = 0; j < 4; j++)
            b[j] = *(const bf16x8*)(&sB[wn * 64 + j * 16 + l15][kg * 8 + ks * 32]);
#pragma unroll
        for (int i = 0; i < 2; i++)
#pragma unroll
            for (int j = 0; j < 4; j++)
                accC[i][j] = __builtin_amdgcn_mfma_f32_16x16x32_bf16(a[i], b[j], accC[i][j], 0, 0, 0);
    }
    __syncthreads();   // everyone done reading sT (T1) ... and phase-A MFMA inputs settled
#pragma unroll
    for (int i = 0; i < 2; i++) {
        int row0 = wm * 32 + i * 16 + kg * 4;
#pragma unroll
        for (int j = 0; j < 4; j++) {
            int col = wn * 64 + j * 16 + l15;
            float bv = bc[col];
#pragma unroll
            for (int r = 0; r < 4; r++)
                sT[row0 + r][col] = f2bf(leaky_f(accC[i][j][r] + bv));   // T2 overwrites T1
        }
    }
    __syncthreads();

    // ---- dec phase B: H2[64][256] = leaky(T2 @ Wc2b + bd), K=128 -> H2t[col][row] ----
    f32x4 accD[2][8];
#pragma unroll
    for (int i = 0; i < 2; i++)
#pragma unroll
        for (int j = 0; j < 8; j++) accD[i][j] = (f32x4){0.f, 0.f, 0.f, 0.f};
    for (int k0 = 0; k0 < 128; k0 += 64) {
#pragma unroll
        for (int it = 0; it < 8; ++it) {
            int idx = tid + it * 256;
            int r = idx >> 3, s = idx & 7;
            *(uint4*)(&sB2[r][s * 8]) = *(const uint4*)(Wd + r * 128 + k0 + s * 8);
        }
        __syncthreads();
#pragma unroll
        for (int ks = 0; ks < 2; ++ks) {
            bf16x8 a[2], b[8];
#pragma unroll
            for (int i = 0; i < 2; i++)
                a[i] = *(const bf16x8*)(&sT[wm * 32 + i * 16 + l15][k0 + ks * 32 + kg * 8]);
#pragma unroll
            for (int j = 0; j < 8; j++)
                b[j] = *(const bf16x8*)(&sB2[wn * 128 + j * 16 + l15][kg * 8 + ks * 32]);
#pragma unroll
            for (int i = 0; i < 2; i++)
#pragma unroll
                for (int j = 0; j < 8; j++)
                    accD[i][j] = __builtin_amdgcn_mfma_f32_16x16x32_bf16(a[i], b[j], accD[i][j], 0, 0, 0);
        }
        __syncthreads();
    }
#pragma unroll
    for (int i = 0; i < 2; i++) {
        int row0 = wm * 32 + i * 16 + kg * 4;
#pragma unroll
        for (int j = 0; j < 8; j++) {
            int col = wn * 128 + j * 16 + l15;
            float bv = bd[col];
            ushort4 tw;
#pragma unroll
            for (int r = 0; r < 4; r++)
                ((unsigned short*)&tw)[r] = f2bf(leaky_f(accD[i][j][r] + bv));
            if ((bm + row0) < M)
                *(ushort4*)(&H2t[(size_t)col * KPAD + bm + row0]) = tw;
        }
    }
}

// ---------------- S2 split-K MFMA: 40 splits of 256 ----------------
__global__ __launch_bounds__(256)
void sgemm_sk(const unsigned short* __restrict__ Zt, const unsigned short* __restrict__ H2t,
              float* __restrict__ part) {
    __shared__ short sA[64][72];
    __shared__ short sB[64][72];
    const int bn = blockIdx.x * 64;
    const int kc = blockIdx.y;
    const int tid = threadIdx.x;
    const int lane = tid & 63, wid = tid >> 6;
    const int wm = wid & 1, wn = wid >> 1;
    const int l15 = lane & 15, kg = lane >> 4;

    f32x4 acc[2][2];
#pragma unroll
    for (int i = 0; i < 2; i++)
#pragma unroll
        for (int j = 0; j < 2; j++) acc[i][j] = (f32x4){0.f, 0.f, 0.f, 0.f};

    for (int kk = 0; kk < 4; ++kk) {
        int k0 = kc * 256 + kk * 64;
#pragma unroll
        for (int it = 0; it < 2; ++it) {
            int idx = tid + it * 256;
            int r = idx >> 3, s = idx & 7;
            *(uint4*)(&sA[r][s * 8]) = *(const uint4*)(Zt + (size_t)r * KPAD + k0 + s * 8);
            *(uint4*)(&sB[r][s * 8]) = *(const uint4*)(H2t + (size_t)(bn + r) * KPAD + k0 + s * 8);
        }
        __syncthreads();
        bf16x8 a[2][2], b[2][2];
#pragma unroll
        for (int i = 0; i < 2; i++)
#pragma unroll
            for (int ks = 0; ks < 2; ++ks) {
                a[i][ks] = *(const bf16x8*)(&sA[wm * 32 + i * 16 + l15][kg * 8 + ks * 32]);
                b[i][ks] = *(const bf16x8*)(&sB[wn * 32 + i * 16 + l15][kg * 8 + ks * 32]);
            }
#pragma unroll
        for (int ks = 0; ks < 2; ++ks)
#pragma unroll
            for (int i = 0; i < 2; i++)
#pragma unroll
                for (int j = 0; j < 2; j++)
                    acc[i][j] = __builtin_amdgcn_mfma_f32_16x16x32_bf16(a[i][ks], b[j][ks], acc[i][j], 0, 0, 0);
        __syncthreads();
    }
#pragma unroll
    for (int i = 0; i < 2; i++) {
        int row0 = wm * 32 + i * 16 + kg * 4;
#pragma unroll
        for (int j = 0; j < 2; j++) {
            int col = bn + wn * 32 + j * 16 + l15;
#pragma unroll
            for (int r = 0; r < 4; r++)
                part[((size_t)kc * 64 + row0 + r) * 256 + col] = acc[i][j][r];
        }
    }
}

// reduce 40 partials -> S2 bf16 [64][256]
__global__ void reduce_S2(const float* __restrict__ part, unsigned short* __restrict__ S2b) {
    int i = blockIdx.x * blockDim.x + threadIdx.x;
    if (i < 64 * 256) {
        float s = 0.f;
#pragma unroll
        for (int c = 0; c < 40; ++c) s += part[(size_t)c * (64 * 256) + i];
        S2b[i] = f2bf(s);
    }
}

// ---------------- launch ----------------
extern "C" void kernel_launch(void* const* d_in, const int* in_sizes, int n_in,
                              void* d_out, int out_size, void* d_ws, size_t ws_size,
                              hipStream_t stream) {
    const float* x    = (const float*)d_in[0];
    const int*   rows = (const int*)d_in[1];
    const int*   cols = (const int*)d_in[2];
    const float* vals = (const float*)d_in[3];
    const float* W1   = (const float*)d_in[4];
    const float* b1   = (const float*)d_in[5];
    const float* Wc1a = (const float*)d_in[6];
    const float* bc1a = (const float*)d_in[7];
    const float* Wc1b = (const float*)d_in[8];
    const float* bc1b = (const float*)d_in[9];
    const float* Wc2a = (const float*)d_in[10];
    const float* bc2a = (const float*)d_in[11];
    const float* Wc2b = (const float*)d_in[12];
    const float* bc2b = (const float*)d_in[13];
    const float* W6   = (const float*)d_in[14];
    const float* b6   = (const float*)d_in[15];

    const int N = NROWS;
    const int E = in_sizes[1];

    float* ws = (float*)d_ws;
    unsigned short* XHI  = (unsigned short*)(ws + 0);         // [10000][512]
    unsigned short* C1b  = (unsigned short*)(ws + 2560000);   // [10000][256]
    unsigned short* HHI  = (unsigned short*)(ws + 3840000);   // [10000][256]
    unsigned short* ZHI  = (unsigned short*)(ws + 5120000);   // [10000][64]
    unsigned short* ZT   = (unsigned short*)(ws + 5440000);   // [64][10240]
    unsigned short* H2T  = (unsigned short*)(ws + 5767680);   // [256][10240]
    float*          PART = ws + 7078400;                      // [40][64][256]
    unsigned short* S2B  = (unsigned short*)(ws + 7733760);   // [64][256]
    unsigned short* W6ST = (unsigned short*)(ws + 7741952);   // [512][64]
    unsigned short* W1T   = (unsigned short*)(ws + 7758336);  // [256][512]
    unsigned short* WC1AT = (unsigned short*)(ws + 7823872);  // [128][256]
    unsigned short* WC1BT = (unsigned short*)(ws + 7840256);  // [64][128]
    unsigned short* WC2AT = (unsigned short*)(ws + 7844352);  // [128][64]
    unsigned short* WC2BT = (unsigned short*)(ws + 7848448);  // [256][128]
    unsigned short* W6T   = (unsigned short*)(ws + 7864832);  // [512][256]

    int*   counts = (int*)(ws + 7930368);
    int*   starts = counts + 10000;
    int*   cursor = starts + 10001;
    int*   cols_s = cursor + 10000;
    float* vals_s = (float*)(cols_s + 320000);

    float* Out = (float*)d_out;
    float* Zp  = (float*)d_out + 5120000;

    const int GX = (N + 63) / 64;  // 157

    conv_all<<<6683, 256, 0, stream>>>(x, W1, Wc1a, Wc1b, Wc2a, Wc2b, W6, XHI,
                                       W1T, WC1AT, WC1BT, WC2AT, WC2BT, W6T,
                                       counts, ZT, H2T);

    hist_kernel<<<(E + 255) / 256, 256, 0, stream>>>(rows, counts, E);
    scan_kernel<<<1, 1024, 0, stream>>>(counts, starts, cursor, N);
    scatter_kernel<<<(E + 255) / 256, 256, 0, stream>>>(rows, cols, vals, cursor, cols_s, vals_s, E);

    // C1 = x @ W1 -> bf16 (64-tile)
    gemm_mfma<0,0,1,0><<<dim3(GX, 4), 256, 0, stream>>>(XHI, W1T, nullptr,
                                                        nullptr, C1b, nullptr, 0, N, 256, 512);

    // H = leaky(spmm + b1) -> bf16 (round-7 exact)
    spmm_leaky_kernel<<<N, 64, 0, stream>>>(starts, cols_s, vals_s, C1b, b1, HHI);

    // fused: z (Zp/ZHI/ZT) + H2^T in one kernel
    fused_encdec<<<GX, 256, 0, stream>>>(HHI, WC1AT, WC1BT, WC2AT, WC2BT,
                                         bc1a, bc1b, bc2a, bc2b,
                                         Zp, ZHI, ZT, H2T, N);

    // S2 = z^T @ H2 (split-K 40) -> PART -> S2B [64][256]
    sgemm_sk<<<dim3(4, 40), 256, 0, stream>>>(ZT, H2T, PART);
    reduce_S2<<<64, 256, 0, stream>>>(PART, S2B);

    // W6S = S2 @ W6 -> W6ST [512][64]
    gemm_mfma<0,0,0,1><<<dim3(1, 8), 256, 0, stream>>>(S2B, W6T, nullptr,
                                                       nullptr, nullptr, W6ST, 64, 64, 512, 256);

    // out = z @ W6S + b6 -> f32 (64-tile)
    gemm_mfma<0,1,0,0><<<dim3(GX, 8), 256, 0, stream>>>(ZHI, W6ST, b6,
                                                        Out, nullptr, nullptr, 0, N, 512, 64);
}